// Round 13
// baseline (176.182 us; speedup 1.0000x reference)
//
#include <hip/hip_runtime.h>

// ChunkwiseRetention: B=8 T=1024 C=1024 NH=16 HD=64
// out[b,t,h*64+d] = GN_b(r)*w[h]+bias[h],  r = (QK^T ∘ decay)V + 1024*Q@past_kv
// current_kv[h] = gamma_h*past_kv[h] + mean_b(K^T V)

#define TKN 8192
#define N3  3072

typedef short short8 __attribute__((ext_vector_type(8)));
typedef float f32x4 __attribute__((ext_vector_type(4)));

static __device__ __forceinline__ unsigned short f2bf(float f){
  unsigned int u = __float_as_uint(f);
  u += 0x7FFFu + ((u >> 16) & 1u);
  return (unsigned short)(u >> 16);
}
static __device__ __forceinline__ float bf2f(unsigned short s){
  return __uint_as_float(((unsigned int)s) << 16);
}
static __device__ __forceinline__ unsigned int cvtpk_bf16(float lo, float hi){
  unsigned int r;
  asm("v_cvt_pk_bf16_f32 %0, %1, %2" : "=v"(r) : "v"(lo), "v"(hi));
  return r;
}
static __device__ __forceinline__ void g2lds16(const void* g, void* l){
  __builtin_amdgcn_global_load_lds(
      (const __attribute__((address_space(1))) unsigned int*)g,
      (__attribute__((address_space(3))) unsigned int*)l, 16, 0, 0);
}

// ---------------- merged conversions ----------------
__global__ __launch_bounds__(256) void k_cvt(const float* __restrict__ x,
                                             const float* __restrict__ w,
                                             const float* __restrict__ pk,
                                             unsigned short* __restrict__ xb,
                                             unsigned short* __restrict__ wt,
                                             unsigned short* __restrict__ pkt){
  __shared__ float tile[64][65];
  const int bid = blockIdx.x;
  if (bid < 2048){
    const int n4 = TKN*1024/4;
    for (int idx = bid*256 + threadIdx.x; idx < n4; idx += 2048*256){
      float4 v = reinterpret_cast<const float4*>(x)[idx];
      uint2 o;
      o.x = cvtpk_bf16(v.x, v.y);
      o.y = cvtpk_bf16(v.z, v.w);
      reinterpret_cast<uint2*>(xb)[idx] = o;
    }
  } else if (bid < 2816){
    const int b2 = bid - 2048;
    const int n0 = (b2 % 48)*64, k0 = (b2 / 48)*64;
    const int tn = threadIdx.x & 63, t4 = threadIdx.x >> 6;
    for (int kk = t4; kk < 64; kk += 4)
      tile[kk][tn] = w[(k0+kk)*N3 + n0 + tn];
    __syncthreads();
    for (int nn = t4; nn < 64; nn += 4)
      wt[(n0+nn)*1024 + k0 + tn] = f2bf(tile[tn][nn]);
  } else {
    int i = (bid - 2816)*256 + threadIdx.x;
    int h = i >> 12, e = (i >> 6) & 63, d = i & 63;
    pkt[i] = f2bf(pk[(h<<12) + (d<<6) + e] * 1024.0f);
  }
}

// ---------------- QKV GEMM: 128x128, BK=32, triple-buffer, counted vmcnt (r6 proven) ----------------
__global__ __launch_bounds__(256, 3) void k_gemm(const unsigned short* __restrict__ A,
                                                 const unsigned short* __restrict__ Bt,
                                                 unsigned short* __restrict__ qb,
                                                 unsigned short* __restrict__ kb,
                                                 unsigned short* __restrict__ vtb){
  __shared__ unsigned short sm[24576];            // 48KB: A bufs 3x8KB | B bufs 3x8KB
  char* smb = (char*)sm;
  const int tid = threadIdx.x;
  const int lane = tid & 63, wid = tid >> 6;
  const int wm = wid >> 1, wn = wid & 1;
  const int n15 = lane & 15, l4 = lane >> 4;
  const int m0 = blockIdx.y * 128;
  const int n0 = blockIdx.x * 128;

  f32x4 acc[4][4] = {};

  // staging: dest line l0 = tid>>2 hosts row r0 = swap01(l0); slot tid&3 holds chunk c.
  const int l0 = tid >> 2;
  const int r0 = (l0 & ~3) | ((l0 & 1) << 1) | ((l0 >> 1) & 1);
  const int c0 = (((tid & 3) ^ ((tid >> 4) & 3)) << 3);   // chunk*8 elems
  #define STAGE(kt, b) do {                                                              \
    g2lds16(A  + (long)(m0 + r0)*1024      + (kt)*32 + c0, smb + (b)*8192 + tid*16);     \
    g2lds16(A  + (long)(m0 + 64 + r0)*1024 + (kt)*32 + c0, smb + (b)*8192 + 4096 + tid*16); \
    g2lds16(Bt + (long)(n0 + r0)*1024      + (kt)*32 + c0, smb + 24576 + (b)*8192 + tid*16); \
    g2lds16(Bt + (long)(n0 + 64 + r0)*1024 + (kt)*32 + c0, smb + 24576 + (b)*8192 + 4096 + tid*16); \
  } while(0)

  STAGE(0, 0);
  STAGE(1, 1);
  asm volatile("s_waitcnt vmcnt(4)" ::: "memory");
  __builtin_amdgcn_s_barrier();

  const int slb = (l4 ^ ((n15 >> 2) & 3)) << 4;   // slot byte (row-invariant)
  int cur = 0;
  for (int t = 0; t < 32; ++t){
    int nb = cur + 2; if (nb >= 3) nb -= 3;
    if (t < 30) STAGE(t + 2, nb);
    const char* ab = smb + cur*8192;
    const char* bb = smb + 24576 + cur*8192;
    short8 a[4], b[4];
    #pragma unroll
    for (int i = 0; i < 4; ++i){
      int ra = wm*64 + i*16 + n15;
      int rs = (ra & ~3) | ((ra & 1) << 1) | ((ra >> 1) & 1);
      a[i] = *(const short8*)(ab + rs*64 + slb);
      int rb = wn*64 + i*16 + n15;
      int rbs = (rb & ~3) | ((rb & 1) << 1) | ((rb >> 1) & 1);
      b[i] = *(const short8*)(bb + rbs*64 + slb);
    }
    __builtin_amdgcn_s_setprio(1);
    #pragma unroll
    for (int i = 0; i < 4; ++i)
      #pragma unroll
      for (int j = 0; j < 4; ++j)
        acc[i][j] = __builtin_amdgcn_mfma_f32_16x16x32_bf16(a[i], b[j], acc[i][j], 0, 0, 0);
    __builtin_amdgcn_s_setprio(0);
    if (t < 30) asm volatile("s_waitcnt vmcnt(4)" ::: "memory");
    else        asm volatile("s_waitcnt vmcnt(0)" ::: "memory");
    __builtin_amdgcn_s_barrier();
    cur = cur + 1; if (cur == 3) cur = 0;
  }
  #undef STAGE

  // conflict-free per-wave epilogue: 8KB scratch [64 rows][128B], XOR-swizzled
  const int bb2 = m0 >> 10;
  const int which = n0 >> 10;                     // 0=q 1=k 2=v
  const int cw = (n0 & 1023) + wn*64;
  const int h = cw >> 6;
  const long bh = (long)(bb2*16 + h);
  const int trow0 = (m0 & 1023) + wm*64;
  char* W = smb + wid*8192;

  if (which < 2){                                 // q,k row-major [b][h][t][64]
    unsigned short* dst = which ? kb : qb;
    #pragma unroll
    for (int mi = 0; mi < 4; ++mi)
      #pragma unroll
      for (int nf = 0; nf < 4; ++nf)
        #pragma unroll
        for (int r = 0; r < 4; ++r){
          int row = mi*16 + l4*4 + r;
          int colb = (nf*32 + 2*n15) ^ ((row & 7) << 4);
          *(unsigned short*)(W + row*128 + colb) = f2bf(acc[mi][nf][r]);
        }
    asm volatile("s_waitcnt lgkmcnt(0)" ::: "memory");
    #pragma unroll
    for (int hh = 0; hh < 2; ++hh)
      #pragma unroll
      for (int c2 = 0; c2 < 4; ++c2){
        int row = hh*32 + (lane >> 1);
        int off = ((lane & 1)*64 + c2*16) ^ ((row & 7) << 4);
        uint4 v = *(const uint4*)(W + row*128 + off);
        int dcol = (lane & 1)*32 + c2*8;
        *(uint4*)(&dst[(bh*1024 + trow0 + row)*64 + dcol]) = v;
      }
  } else {                                        // v transposed [b][h][d][t]
    #pragma unroll
    for (int mi = 0; mi < 4; ++mi)
      #pragma unroll
      for (int nf = 0; nf < 4; ++nf)
        #pragma unroll
        for (int r = 0; r < 4; ++r){
          int dl = nf*16 + n15;
          int row = mi*16 + l4*4 + r;
          int colb = (2*row) ^ ((dl & 7) << 4);
          *(unsigned short*)(W + dl*128 + colb) = f2bf(acc[mi][nf][r]);
        }
    asm volatile("s_waitcnt lgkmcnt(0)" ::: "memory");
    #pragma unroll
    for (int hh = 0; hh < 2; ++hh)
      #pragma unroll
      for (int c2 = 0; c2 < 4; ++c2){
        int dl = hh*32 + (lane >> 1);
        int off = ((lane & 1)*64 + c2*16) ^ ((dl & 7) << 4);
        uint4 v = *(const uint4*)(W + dl*128 + off);
        int tcol = (lane & 1)*32 + c2*8;
        *(uint4*)(&vtb[(bh*64 + dl)*1024 + trow0 + tcol]) = v;
      }
  }
}

// ---------------- attention: 1024 blocks (one q-tile each, LPT order), depth-2 prefetch ----------------
__global__ __launch_bounds__(256) void k_attn(const unsigned short* __restrict__ qb,
                                              const unsigned short* __restrict__ kb,
                                              const unsigned short* __restrict__ vtb,
                                              const unsigned short* __restrict__ pkt,
                                              unsigned short* __restrict__ rb,
                                              float* __restrict__ gnp){
  __shared__ unsigned short Qs[8192];             // 16KB; doubles as K/V buffer 2
  __shared__ unsigned short Kd[2][4096];
  __shared__ unsigned short Vd[2][4096];
  __shared__ unsigned short Ps[8192];
  __shared__ float gred[2][4];
  const int id = blockIdx.x;                      // 1024 blocks, 1024%8==0
  const int lin = (id & 7)*128 + (id >> 3);       // per-XCD chunk: 16 bh (K+V = 4MB = one L2)
  const int qt = 7 - (lin & 7);                   // longest-first (LPT) within chunk
  const int bh = lin >> 3;
  const int h = bh & 15;
  const int tid = threadIdx.x;
  const int lane = tid & 63, wid = tid >> 6;
  const int n15 = lane & 15, l4 = lane >> 4;
  const unsigned short* qp = qb + (long)bh*65536;
  const unsigned short* kp = kb + (long)bh*65536;
  const unsigned short* vp = vtb + (long)bh*65536;
  const float lg = log2f(1.0f - exp2f(-5.0f - (float)h));
  const int srow = tid >> 3, schunk = tid & 7;

  char* const kb0 = (char*)Kd[0]; char* const kb1 = (char*)Kd[1]; char* const kb2 = (char*)Qs;
  char* const vb0 = (char*)Vd[0]; char* const vb1 = (char*)Vd[1]; char* const vb2 = (char*)Qs + 8192;

  float kvE[4][4];
  #pragma unroll
  for (int i = 0; i < 4; ++i)
    #pragma unroll
    for (int r = 0; r < 4; ++r)
      kvE[i][r] = exp2f(-lg * (float)(i*16 + l4*4 + r));

  float gs = 0.f, gq = 0.f;
  unsigned short* rp = rb + (long)bh*65536;

  const int t0 = qt * 128;
  const int jmax = 2*qt + 1;
  // prologue: Q(4), PKt+K0+V0(6), K1+V1(4) -> wait first 10, leave 4 in flight
  for (int c = 0; c < 4; ++c){
    int r = c*32 + srow;
    int src = schunk ^ (r & 7);
    g2lds16(qp + (long)(t0 + r)*64 + src*8, (char*)Qs + c*4096 + tid*16);
  }
  for (int c = 0; c < 2; ++c){
    int r = c*32 + srow;
    int src = schunk ^ (r & 7);
    g2lds16(pkt + (long)(h*64 + r)*64 + src*8, (char*)Ps + c*4096 + tid*16);
    g2lds16(kp + (long)r*64 + src*8, kb0 + c*4096 + tid*16);
    g2lds16(vp + (long)r*1024 + src*8, vb0 + c*4096 + tid*16);
  }
  for (int c = 0; c < 2; ++c){
    int r = c*32 + srow;
    int src = schunk ^ (r & 7);
    g2lds16(kp + (long)(64 + r)*64 + src*8, kb1 + c*4096 + tid*16);
    g2lds16(vp + (long)r*1024 + 64 + src*8, vb1 + c*4096 + tid*16);
  }
  asm volatile("s_waitcnt vmcnt(4)" ::: "memory");
  __syncthreads();

  short8 aq[2][2];
  #pragma unroll
  for (int mf = 0; mf < 2; ++mf)
    #pragma unroll
    for (int kk = 0; kk < 2; ++kk){
      int r = wid*32 + mf*16 + n15;
      int sl = (kk*4 + l4) ^ (r & 7);
      aq[mf][kk] = *reinterpret_cast<const short8*>((const char*)Qs + r*128 + sl*16);
    }

  f32x4 o[2][4] = {};
  #pragma unroll
  for (int kk = 0; kk < 2; ++kk){
    short8 bpk[4];
    #pragma unroll
    for (int nf = 0; nf < 4; ++nf){
      int r = nf*16 + n15;
      int sl = (kk*4 + l4) ^ (r & 7);
      bpk[nf] = *reinterpret_cast<const short8*>((const char*)Ps + r*128 + sl*16);
    }
    #pragma unroll
    for (int mf = 0; mf < 2; ++mf)
      #pragma unroll
      for (int nf = 0; nf < 4; ++nf)
        o[mf][nf] = __builtin_amdgcn_mfma_f32_16x16x32_bf16(aq[mf][kk], bpk[nf], o[mf][nf], 0,0,0);
  }
  __syncthreads();                                // aq + Ps(PKt) reads done -> Qs/Ps reusable

  int curb = 0, sjb = 2;                          // j%3, (j+2)%3
  for (int j = 0; j <= jmax; ++j){
    const int kv0 = j*64;
    const bool willstage = (j + 2 <= jmax);
    if (willstage){
      const int kvn = kv0 + 128;
      char* kbs = (sjb == 0) ? kb0 : ((sjb == 1) ? kb1 : kb2);
      char* vbs = (sjb == 0) ? vb0 : ((sjb == 1) ? vb1 : vb2);
      for (int c = 0; c < 2; ++c){
        int r = c*32 + srow;
        int src = schunk ^ (r & 7);
        g2lds16(kp + (long)(kvn + r)*64 + src*8, kbs + c*4096 + tid*16);
        g2lds16(vp + (long)r*1024 + kvn + src*8, vbs + c*4096 + tid*16);
      }
    }
    const bool active = (kv0 <= t0 + wid*32 + 31);
    if (active){
      const char* kcur = (curb == 0) ? kb0 : ((curb == 1) ? kb1 : kb2);
      const char* vcur = (curb == 0) ? vb0 : ((curb == 1) ? vb1 : vb2);
      f32x4 sT[4][2] = {};
      #pragma unroll
      for (int kk = 0; kk < 2; ++kk){
        short8 bk[4];
        #pragma unroll
        for (int i = 0; i < 4; ++i){
          int r = i*16 + n15;
          int sl = (kk*4 + l4) ^ (r & 7);
          bk[i] = *reinterpret_cast<const short8*>(kcur + r*128 + sl*16);
        }
        #pragma unroll
        for (int i = 0; i < 4; ++i)
          #pragma unroll
          for (int mf = 0; mf < 2; ++mf)
            sT[i][mf] = __builtin_amdgcn_mfma_f32_16x16x32_bf16(bk[i], aq[mf][kk], sT[i][mf], 0,0,0);
      }
      const bool diag = (kv0 + 63 > t0 + wid*32);
      #pragma unroll
      for (int mf = 0; mf < 2; ++mf){
        const int trow = wid*32 + mf*16 + n15;
        const float rowE = exp2f(lg * (float)(t0 + trow - kv0));
        char* wb = (char*)Ps + trow*128;
        const int swz = (trow & 7) << 4;
        #pragma unroll
        for (int i = 0; i < 4; ++i){
          float v0 = sT[i][mf][0] * (rowE * kvE[i][0]);
          float v1 = sT[i][mf][1] * (rowE * kvE[i][1]);
          float v2 = sT[i][mf][2] * (rowE * kvE[i][2]);
          float v3 = sT[i][mf][3] * (rowE * kvE[i][3]);
          if (diag){
            int dd = (t0 + trow) - (kv0 + i*16 + l4*4);
            if (dd < 0) v0 = 0.f;
            if (dd < 1) v1 = 0.f;
            if (dd < 2) v2 = 0.f;
            if (dd < 3) v3 = 0.f;
          }
          uint2 pw;
          pw.x = cvtpk_bf16(v0, v1);
          pw.y = cvtpk_bf16(v2, v3);
          *(uint2*)(wb + ((i*32 + l4*8) ^ swz)) = pw;
        }
      }
      #pragma unroll
      for (int kk = 0; kk < 2; ++kk){
        short8 ap[2], bv[4];
        #pragma unroll
        for (int mf = 0; mf < 2; ++mf){
          int r = wid*32 + mf*16 + n15;
          int sl = (kk*4 + l4) ^ (r & 7);
          ap[mf] = *reinterpret_cast<const short8*>((const char*)Ps + r*128 + sl*16);
        }
        #pragma unroll
        for (int nf = 0; nf < 4; ++nf){
          int r = nf*16 + n15;
          int sl = (kk*4 + l4) ^ (r & 7);
          bv[nf] = *reinterpret_cast<const short8*>(vcur + r*128 + sl*16);
        }
        #pragma unroll
        for (int mf = 0; mf < 2; ++mf)
          #pragma unroll
          for (int nf = 0; nf < 4; ++nf)
            o[mf][nf] = __builtin_amdgcn_mfma_f32_16x16x32_bf16(ap[mf], bv[nf], o[mf][nf], 0,0,0);
      }
    }
    if (willstage) asm volatile("s_waitcnt vmcnt(4)" ::: "memory");
    else           asm volatile("s_waitcnt vmcnt(0)" ::: "memory");
    __syncthreads();
    curb = (curb == 2) ? 0 : curb + 1;
    sjb  = (sjb  == 2) ? 0 : sjb  + 1;
  }
  // epilogue: o -> Ps (wave-local, swizzled) -> coalesced global; + GN partials
  #pragma unroll
  for (int mf = 0; mf < 2; ++mf)
    #pragma unroll
    for (int nf = 0; nf < 4; ++nf)
      #pragma unroll
      for (int r = 0; r < 4; ++r){
        int trow = wid*32 + mf*16 + l4*4 + r;
        int d = nf*16 + n15;
        float v = o[mf][nf][r];
        gs += v; gq += v*v;
        *(unsigned short*)((char*)Ps + trow*128 + ((2*d) ^ ((trow & 7) << 4))) = f2bf(v);
      }
  asm volatile("s_waitcnt lgkmcnt(0)" ::: "memory");
  #pragma unroll
  for (int rr = 0; rr < 4; ++rr){
    int row = wid*32 + rr*8 + (lane >> 3);
    int off = (((lane & 7) << 4) ^ ((row & 7) << 4));
    uint4 v = *(const uint4*)((const char*)Ps + row*128 + off);
    *(uint4*)(rp + (long)(t0 + row)*64 + ((lane & 7) << 3)) = v;
  }
  #pragma unroll
  for (int off = 32; off > 0; off >>= 1){
    gs += __shfl_down(gs, off);
    gq += __shfl_down(gq, off);
  }
  if (lane == 0){ gred[0][wid] = gs; gred[1][wid] = gq; }
  __syncthreads();
  if (tid == 0){
    gnp[(bh*8 + qt)*2]   = gred[0][0]+gred[0][1]+gred[0][2]+gred[0][3];
    gnp[(bh*8 + qt)*2+1] = gred[1][0]+gred[1][1]+gred[1][2]+gred[1][3];
  }
}

// ---------------- K^T V partials (LDS-transpose vector-FMA) ----------------
__global__ __launch_bounds__(256) void k_kvpart(const unsigned short* __restrict__ kb,
                                                const unsigned short* __restrict__ vtb,
                                                float* __restrict__ part){
  __shared__ unsigned short Kt[64*64];
  __shared__ unsigned int   Vt32[64*33];
  const int id = blockIdx.x;
  const int lin = (id & 7)*64 + (id >> 3);
  const int tc = lin & 3, bh = lin >> 2;
  const int tid = threadIdx.x;
  const int d0 = (tid >> 4) << 2;
  const int e0 = (tid & 15) << 2;
  const unsigned short* kp = kb + (long)bh*65536;
  const unsigned short* vp = vtb + (long)bh*65536;
  float acc[4][4] = {{0.f}};
  for (int tt = 0; tt < 4; ++tt){
    const int tb = tc*256 + tt*64;
    __syncthreads();
    {
      int rr0 = tid >> 3, off = (tid & 7) * 8;
      for (int c = 0; c < 2; ++c){
        int r = c*32 + rr0;
        *reinterpret_cast<uint4*>(&Kt[r*64 + off]) =
            *reinterpret_cast<const uint4*>(&kp[(long)(tb + r)*64 + off]);
        uint4 vv = *reinterpret_cast<const uint4*>(&vp[(long)r*1024 + tb + off]);
        unsigned int* dv = &Vt32[r*33 + (off >> 1)];
        dv[0] = vv.x; dv[1] = vv.y; dv[2] = vv.z; dv[3] = vv.w;
      }
    }
    __syncthreads();
    const unsigned short* Vt = (const unsigned short*)Vt32;
    for (int t = 0; t < 64; ++t){
      float kv[4], vv[4];
      #pragma unroll
      for (int i = 0; i < 4; ++i) kv[i] = bf2f(Kt[t*64 + d0 + i]);
      #pragma unroll
      for (int i = 0; i < 4; ++i) vv[i] = bf2f(Vt[(e0 + i)*66 + t]);
      #pragma unroll
      for (int i = 0; i < 4; ++i)
        #pragma unroll
        for (int j = 0; j < 4; ++j) acc[i][j] += kv[i]*vv[j];
    }
  }
  float* pp = part + ((long)(tc*128 + bh) << 12);
  for (int i = 0; i < 4; ++i)
    for (int j = 0; j < 4; ++j)
      pp[(d0+i)*64 + e0 + j] = acc[i][j];
}

// kvfin + GroupNorm stage-2 fused (128 groups per batch now)
__global__ __launch_bounds__(256) void k_kvfin(const float* __restrict__ part,
                                               const float* __restrict__ pk,
                                               float* __restrict__ okv,
                                               const float* __restrict__ gnp,
                                               float* __restrict__ musig){
  if (blockIdx.x == 0 && threadIdx.x < 8){
    int b = threadIdx.x;
    float S = 0.f, Q = 0.f;
    for (int g = 0; g < 128; ++g){ S += gnp[b*256 + g*2]; Q += gnp[b*256 + g*2 + 1]; }
    float mu  = S * (1.0f/1048576.0f);
    float var = Q * (1.0f/1048576.0f) - mu*mu;
    musig[b*2]   = mu;
    musig[b*2+1] = rsqrtf(var + 1e-5f);
  }
  int i = blockIdx.x*256 + threadIdx.x;
  int h = i >> 12;
  float acc = 0.f;
  for (int tc = 0; tc < 4; ++tc)
    for (int b = 0; b < 8; ++b)
      acc += part[((long)(tc*128 + b*16 + h) << 12) + (i & 4095)];
  float gamma = 1.0f - exp2f(-5.0f - (float)h);
  okv[i] = gamma * pk[i] + acc * 0.125f;
}

__global__ __launch_bounds__(256) void k_gnnorm(const unsigned short* __restrict__ rbuf,
                                                const float* __restrict__ musig,
                                                const float* __restrict__ gw,
                                                const float* __restrict__ gb,
                                                float* __restrict__ out){
  const int n8 = TKN*1024/8;
  for (int idx = blockIdx.x*256 + threadIdx.x; idx < n8; idx += gridDim.x*256){
    int o = idx*8;
    int c = o & 1023;
    int t = (o >> 10) & 1023;
    int b = o >> 20;
    int h = c >> 6, d = c & 63;
    short8 v = *reinterpret_cast<const short8*>(rbuf + ((long)(b*16 + h) << 16) + t*64 + d);
    float rs = musig[b*2+1];
    float a = gw[h]*rs, b2 = gb[h] - musig[b*2]*a;
    float4 o0, o1;
    o0.x = bf2f((unsigned short)v[0])*a + b2;
    o0.y = bf2f((unsigned short)v[1])*a + b2;
    o0.z = bf2f((unsigned short)v[2])*a + b2;
    o0.w = bf2f((unsigned short)v[3])*a + b2;
    o1.x = bf2f((unsigned short)v[4])*a + b2;
    o1.y = bf2f((unsigned short)v[5])*a + b2;
    o1.z = bf2f((unsigned short)v[6])*a + b2;
    o1.w = bf2f((unsigned short)v[7])*a + b2;
    *reinterpret_cast<float4*>(out + o)     = o0;
    *reinterpret_cast<float4*>(out + o + 4) = o1;
  }
}

extern "C" void kernel_launch(void* const* d_in, const int* in_sizes, int n_in,
                              void* d_out, int out_size, void* d_ws, size_t ws_size,
                              hipStream_t stream){
  const float* x  = (const float*)d_in[0];
  const float* pk = (const float*)d_in[1];
  const float* w  = (const float*)d_in[2];
  const float* gw = (const float*)d_in[3];
  const float* gb = (const float*)d_in[4];
  float* out = (float*)d_out;
  char* ws = (char*)d_ws;

  unsigned short* Xb  = (unsigned short*)(ws);                 // 16 MB (aliased by KVp later)
  unsigned short* WTb = (unsigned short*)(ws + 16777216);      //  6 MB
  unsigned short* Qb  = (unsigned short*)(ws + 23068672);      // 16 MB
  unsigned short* Kb  = (unsigned short*)(ws + 39845888);      // 16 MB
  unsigned short* VTb = (unsigned short*)(ws + 56623104);      // 16 MB
  unsigned short* PKt = (unsigned short*)(ws + 73400320);      // 128 KB
  unsigned short* Rb  = (unsigned short*)(ws + 73531392);      // 16 MB (bf16)
  float* KVp = (float*)(ws);                                   // aliases Xb (dead after gemm)
  float* GNp = (float*)(ws + 90308608);                        // 8 KB
  float* MuS = (float*)(ws + 90316800);                        // 64 B

  k_cvt    <<<dim3(3072),    dim3(256), 0, stream>>>(x, w, pk, Xb, WTb, PKt);
  k_gemm   <<<dim3(24, 64),  dim3(256), 0, stream>>>(Xb, WTb, Qb, Kb, VTb);
  k_kvpart <<<dim3(512),     dim3(256), 0, stream>>>(Kb, VTb, KVp);
  k_attn   <<<dim3(1024),    dim3(256), 0, stream>>>(Qb, Kb, VTb, PKt, Rb, GNp);
  k_kvfin  <<<dim3(256),     dim3(256), 0, stream>>>(KVp, pk, out + 8388608, GNp, MuS);
  k_gnnorm <<<dim3(1024),    dim3(256), 0, stream>>>(Rb, MuS, gw, gb, out);
}

// Round 14
// 155.937 us; speedup vs baseline: 1.1298x; 1.1298x over previous
//
#include <hip/hip_runtime.h>

// ChunkwiseRetention: B=8 T=1024 C=1024 NH=16 HD=64
// out[b,t,h*64+d] = GN_b(r)*w[h]+bias[h],  r = (QK^T ∘ decay)V + 1024*Q@past_kv
// current_kv[h] = gamma_h*past_kv[h] + mean_b(K^T V)

#define TKN 8192
#define N3  3072

typedef short short8 __attribute__((ext_vector_type(8)));
typedef float f32x4 __attribute__((ext_vector_type(4)));

static __device__ __forceinline__ unsigned short f2bf(float f){
  unsigned int u = __float_as_uint(f);
  u += 0x7FFFu + ((u >> 16) & 1u);
  return (unsigned short)(u >> 16);
}
static __device__ __forceinline__ float bf2f(unsigned short s){
  return __uint_as_float(((unsigned int)s) << 16);
}
static __device__ __forceinline__ unsigned int cvtpk_bf16(float lo, float hi){
  unsigned int r;
  asm("v_cvt_pk_bf16_f32 %0, %1, %2" : "=v"(r) : "v"(lo), "v"(hi));
  return r;
}
static __device__ __forceinline__ void g2lds16(const void* g, void* l){
  __builtin_amdgcn_global_load_lds(
      (const __attribute__((address_space(1))) unsigned int*)g,
      (__attribute__((address_space(3))) unsigned int*)l, 16, 0, 0);
}

// ---------------- merged conversions ----------------
__global__ __launch_bounds__(256) void k_cvt(const float* __restrict__ x,
                                             const float* __restrict__ w,
                                             const float* __restrict__ pk,
                                             unsigned short* __restrict__ xb,
                                             unsigned short* __restrict__ wt,
                                             unsigned short* __restrict__ pkt){
  __shared__ float tile[64][65];
  const int bid = blockIdx.x;
  if (bid < 2048){
    const int n4 = TKN*1024/4;
    for (int idx = bid*256 + threadIdx.x; idx < n4; idx += 2048*256){
      float4 v = reinterpret_cast<const float4*>(x)[idx];
      uint2 o;
      o.x = cvtpk_bf16(v.x, v.y);
      o.y = cvtpk_bf16(v.z, v.w);
      reinterpret_cast<uint2*>(xb)[idx] = o;
    }
  } else if (bid < 2816){
    const int b2 = bid - 2048;
    const int n0 = (b2 % 48)*64, k0 = (b2 / 48)*64;
    const int tn = threadIdx.x & 63, t4 = threadIdx.x >> 6;
    for (int kk = t4; kk < 64; kk += 4)
      tile[kk][tn] = w[(k0+kk)*N3 + n0 + tn];
    __syncthreads();
    for (int nn = t4; nn < 64; nn += 4)
      wt[(n0+nn)*1024 + k0 + tn] = f2bf(tile[tn][nn]);
  } else {
    int i = (bid - 2816)*256 + threadIdx.x;
    int h = i >> 12, e = (i >> 6) & 63, d = i & 63;
    pkt[i] = f2bf(pk[(h<<12) + (d<<6) + e] * 1024.0f);
  }
}

// ---------------- QKV GEMM: 128x128, BK=32, triple-buffer, counted vmcnt (r6 proven) ----------------
__global__ __launch_bounds__(256, 3) void k_gemm(const unsigned short* __restrict__ A,
                                                 const unsigned short* __restrict__ Bt,
                                                 unsigned short* __restrict__ qb,
                                                 unsigned short* __restrict__ kb,
                                                 unsigned short* __restrict__ vtb){
  __shared__ unsigned short sm[24576];            // 48KB: A bufs 3x8KB | B bufs 3x8KB
  char* smb = (char*)sm;
  const int tid = threadIdx.x;
  const int lane = tid & 63, wid = tid >> 6;
  const int wm = wid >> 1, wn = wid & 1;
  const int n15 = lane & 15, l4 = lane >> 4;
  const int m0 = blockIdx.y * 128;
  const int n0 = blockIdx.x * 128;

  f32x4 acc[4][4] = {};

  // staging: dest line l0 = tid>>2 hosts row r0 = swap01(l0); slot tid&3 holds chunk c.
  const int l0 = tid >> 2;
  const int r0 = (l0 & ~3) | ((l0 & 1) << 1) | ((l0 >> 1) & 1);
  const int c0 = (((tid & 3) ^ ((tid >> 4) & 3)) << 3);   // chunk*8 elems
  #define STAGE(kt, b) do {                                                              \
    g2lds16(A  + (long)(m0 + r0)*1024      + (kt)*32 + c0, smb + (b)*8192 + tid*16);     \
    g2lds16(A  + (long)(m0 + 64 + r0)*1024 + (kt)*32 + c0, smb + (b)*8192 + 4096 + tid*16); \
    g2lds16(Bt + (long)(n0 + r0)*1024      + (kt)*32 + c0, smb + 24576 + (b)*8192 + tid*16); \
    g2lds16(Bt + (long)(n0 + 64 + r0)*1024 + (kt)*32 + c0, smb + 24576 + (b)*8192 + 4096 + tid*16); \
  } while(0)

  STAGE(0, 0);
  STAGE(1, 1);
  asm volatile("s_waitcnt vmcnt(4)" ::: "memory");
  __builtin_amdgcn_s_barrier();

  const int slb = (l4 ^ ((n15 >> 2) & 3)) << 4;   // slot byte (row-invariant)
  int cur = 0;
  for (int t = 0; t < 32; ++t){
    int nb = cur + 2; if (nb >= 3) nb -= 3;
    if (t < 30) STAGE(t + 2, nb);
    const char* ab = smb + cur*8192;
    const char* bb = smb + 24576 + cur*8192;
    short8 a[4], b[4];
    #pragma unroll
    for (int i = 0; i < 4; ++i){
      int ra = wm*64 + i*16 + n15;
      int rs = (ra & ~3) | ((ra & 1) << 1) | ((ra >> 1) & 1);
      a[i] = *(const short8*)(ab + rs*64 + slb);
      int rb = wn*64 + i*16 + n15;
      int rbs = (rb & ~3) | ((rb & 1) << 1) | ((rb >> 1) & 1);
      b[i] = *(const short8*)(bb + rbs*64 + slb);
    }
    __builtin_amdgcn_s_setprio(1);
    #pragma unroll
    for (int i = 0; i < 4; ++i)
      #pragma unroll
      for (int j = 0; j < 4; ++j)
        acc[i][j] = __builtin_amdgcn_mfma_f32_16x16x32_bf16(a[i], b[j], acc[i][j], 0, 0, 0);
    __builtin_amdgcn_s_setprio(0);
    if (t < 30) asm volatile("s_waitcnt vmcnt(4)" ::: "memory");
    else        asm volatile("s_waitcnt vmcnt(0)" ::: "memory");
    __builtin_amdgcn_s_barrier();
    cur = cur + 1; if (cur == 3) cur = 0;
  }
  #undef STAGE

  // conflict-free per-wave epilogue: 8KB scratch [64 rows][128B], XOR-swizzled
  const int bb2 = m0 >> 10;
  const int which = n0 >> 10;                     // 0=q 1=k 2=v
  const int cw = (n0 & 1023) + wn*64;
  const int h = cw >> 6;
  const long bh = (long)(bb2*16 + h);
  const int trow0 = (m0 & 1023) + wm*64;
  char* W = smb + wid*8192;

  if (which < 2){                                 // q,k row-major [b][h][t][64]
    unsigned short* dst = which ? kb : qb;
    #pragma unroll
    for (int mi = 0; mi < 4; ++mi)
      #pragma unroll
      for (int nf = 0; nf < 4; ++nf)
        #pragma unroll
        for (int r = 0; r < 4; ++r){
          int row = mi*16 + l4*4 + r;
          int colb = (nf*32 + 2*n15) ^ ((row & 7) << 4);
          *(unsigned short*)(W + row*128 + colb) = f2bf(acc[mi][nf][r]);
        }
    asm volatile("s_waitcnt lgkmcnt(0)" ::: "memory");
    #pragma unroll
    for (int hh = 0; hh < 2; ++hh)
      #pragma unroll
      for (int c2 = 0; c2 < 4; ++c2){
        int row = hh*32 + (lane >> 1);
        int off = ((lane & 1)*64 + c2*16) ^ ((row & 7) << 4);
        uint4 v = *(const uint4*)(W + row*128 + off);
        int dcol = (lane & 1)*32 + c2*8;
        *(uint4*)(&dst[(bh*1024 + trow0 + row)*64 + dcol]) = v;
      }
  } else {                                        // v transposed [b][h][d][t]
    #pragma unroll
    for (int mi = 0; mi < 4; ++mi)
      #pragma unroll
      for (int nf = 0; nf < 4; ++nf)
        #pragma unroll
        for (int r = 0; r < 4; ++r){
          int dl = nf*16 + n15;
          int row = mi*16 + l4*4 + r;
          int colb = (2*row) ^ ((dl & 7) << 4);
          *(unsigned short*)(W + dl*128 + colb) = f2bf(acc[mi][nf][r]);
        }
    asm volatile("s_waitcnt lgkmcnt(0)" ::: "memory");
    #pragma unroll
    for (int hh = 0; hh < 2; ++hh)
      #pragma unroll
      for (int c2 = 0; c2 < 4; ++c2){
        int dl = hh*32 + (lane >> 1);
        int off = ((lane & 1)*64 + c2*16) ^ ((dl & 7) << 4);
        uint4 v = *(const uint4*)(W + dl*128 + off);
        int tcol = (lane & 1)*32 + c2*8;
        *(uint4*)(&vtb[(bh*64 + dl)*1024 + trow0 + tcol]) = v;
      }
  }
}

// ---------------- attention: swapped QK^T, counted-vmcnt depth-2 K/V prefetch, cvt_pk P ----------------
__global__ __launch_bounds__(256) void k_attn(const unsigned short* __restrict__ qb,
                                              const unsigned short* __restrict__ kb,
                                              const unsigned short* __restrict__ vtb,
                                              const unsigned short* __restrict__ pkt,
                                              unsigned short* __restrict__ rb,
                                              float* __restrict__ gnp){
  __shared__ unsigned short Qs[8192];             // 16KB; doubles as K/V buffer 2
  __shared__ unsigned short Kd[2][4096];
  __shared__ unsigned short Vd[2][4096];
  __shared__ unsigned short Ps[8192];
  __shared__ float gred[2][4];
  const int id = blockIdx.x;                      // 512 blocks, 512%8==0
  const int lin = (id & 7)*64 + (id >> 3);
  const int qpair = lin & 3;
  const int bh = lin >> 2;
  const int h = bh & 15;
  const int tid = threadIdx.x;
  const int lane = tid & 63, wid = tid >> 6;
  const int n15 = lane & 15, l4 = lane >> 4;
  const unsigned short* qp = qb + (long)bh*65536;
  const unsigned short* kp = kb + (long)bh*65536;
  const unsigned short* vp = vtb + (long)bh*65536;
  const float lg = log2f(1.0f - exp2f(-5.0f - (float)h));
  const int srow = tid >> 3, schunk = tid & 7;

  char* const kb0 = (char*)Kd[0]; char* const kb1 = (char*)Kd[1]; char* const kb2 = (char*)Qs;
  char* const vb0 = (char*)Vd[0]; char* const vb1 = (char*)Vd[1]; char* const vb2 = (char*)Qs + 8192;

  float kvE[4][4];
  #pragma unroll
  for (int i = 0; i < 4; ++i)
    #pragma unroll
    for (int r = 0; r < 4; ++r)
      kvE[i][r] = exp2f(-lg * (float)(i*16 + l4*4 + r));

  float gs = 0.f, gq = 0.f;
  unsigned short* rp = rb + (long)bh*65536;

  for (int p = 0; p < 2; ++p){
    const int qt = p ? (7 - qpair) : qpair;
    const int t0 = qt * 128;
    const int jmax = 2*qt + 1;
    for (int c = 0; c < 4; ++c){
      int r = c*32 + srow;
      int src = schunk ^ (r & 7);
      g2lds16(qp + (long)(t0 + r)*64 + src*8, (char*)Qs + c*4096 + tid*16);
    }
    for (int c = 0; c < 2; ++c){
      int r = c*32 + srow;
      int src = schunk ^ (r & 7);
      g2lds16(pkt + (long)(h*64 + r)*64 + src*8, (char*)Ps + c*4096 + tid*16);
      g2lds16(kp + (long)r*64 + src*8, kb0 + c*4096 + tid*16);
      g2lds16(vp + (long)r*1024 + src*8, vb0 + c*4096 + tid*16);
    }
    for (int c = 0; c < 2; ++c){
      int r = c*32 + srow;
      int src = schunk ^ (r & 7);
      g2lds16(kp + (long)(64 + r)*64 + src*8, kb1 + c*4096 + tid*16);
      g2lds16(vp + (long)r*1024 + 64 + src*8, vb1 + c*4096 + tid*16);
    }
    asm volatile("s_waitcnt vmcnt(4)" ::: "memory");
    __syncthreads();

    short8 aq[2][2];
    #pragma unroll
    for (int mf = 0; mf < 2; ++mf)
      #pragma unroll
      for (int kk = 0; kk < 2; ++kk){
        int r = wid*32 + mf*16 + n15;
        int sl = (kk*4 + l4) ^ (r & 7);
        aq[mf][kk] = *reinterpret_cast<const short8*>((const char*)Qs + r*128 + sl*16);
      }

    f32x4 o[2][4] = {};
    #pragma unroll
    for (int kk = 0; kk < 2; ++kk){
      short8 bpk[4];
      #pragma unroll
      for (int nf = 0; nf < 4; ++nf){
        int r = nf*16 + n15;
        int sl = (kk*4 + l4) ^ (r & 7);
        bpk[nf] = *reinterpret_cast<const short8*>((const char*)Ps + r*128 + sl*16);
      }
      #pragma unroll
      for (int mf = 0; mf < 2; ++mf)
        #pragma unroll
        for (int nf = 0; nf < 4; ++nf)
          o[mf][nf] = __builtin_amdgcn_mfma_f32_16x16x32_bf16(aq[mf][kk], bpk[nf], o[mf][nf], 0,0,0);
    }
    __syncthreads();                              // aq + Ps(PKt) reads done -> Qs/Ps reusable

    int curb = 0, sjb = 2;                        // j%3, (j+2)%3
    for (int j = 0; j <= jmax; ++j){
      const int kv0 = j*64;
      const bool willstage = (j + 2 <= jmax);
      if (willstage){
        const int kvn = kv0 + 128;
        char* kbs = (sjb == 0) ? kb0 : ((sjb == 1) ? kb1 : kb2);
        char* vbs = (sjb == 0) ? vb0 : ((sjb == 1) ? vb1 : vb2);
        for (int c = 0; c < 2; ++c){
          int r = c*32 + srow;
          int src = schunk ^ (r & 7);
          g2lds16(kp + (long)(kvn + r)*64 + src*8, kbs + c*4096 + tid*16);
          g2lds16(vp + (long)r*1024 + kvn + src*8, vbs + c*4096 + tid*16);
        }
      }
      const bool active = (kv0 <= t0 + wid*32 + 31);
      if (active){
        const char* kcur = (curb == 0) ? kb0 : ((curb == 1) ? kb1 : kb2);
        const char* vcur = (curb == 0) ? vb0 : ((curb == 1) ? vb1 : vb2);
        f32x4 sT[4][2] = {};
        #pragma unroll
        for (int kk = 0; kk < 2; ++kk){
          short8 bk[4];
          #pragma unroll
          for (int i = 0; i < 4; ++i){
            int r = i*16 + n15;
            int sl = (kk*4 + l4) ^ (r & 7);
            bk[i] = *reinterpret_cast<const short8*>(kcur + r*128 + sl*16);
          }
          #pragma unroll
          for (int i = 0; i < 4; ++i)
            #pragma unroll
            for (int mf = 0; mf < 2; ++mf)
              sT[i][mf] = __builtin_amdgcn_mfma_f32_16x16x32_bf16(bk[i], aq[mf][kk], sT[i][mf], 0,0,0);
        }
        const bool diag = (kv0 + 63 > t0 + wid*32);
        #pragma unroll
        for (int mf = 0; mf < 2; ++mf){
          const int trow = wid*32 + mf*16 + n15;
          const float rowE = exp2f(lg * (float)(t0 + trow - kv0));
          char* wb = (char*)Ps + trow*128;
          const int swz = (trow & 7) << 4;
          #pragma unroll
          for (int i = 0; i < 4; ++i){
            float v0 = sT[i][mf][0] * (rowE * kvE[i][0]);
            float v1 = sT[i][mf][1] * (rowE * kvE[i][1]);
            float v2 = sT[i][mf][2] * (rowE * kvE[i][2]);
            float v3 = sT[i][mf][3] * (rowE * kvE[i][3]);
            if (diag){
              int dd = (t0 + trow) - (kv0 + i*16 + l4*4);
              if (dd < 0) v0 = 0.f;
              if (dd < 1) v1 = 0.f;
              if (dd < 2) v2 = 0.f;
              if (dd < 3) v3 = 0.f;
            }
            uint2 pw;
            pw.x = cvtpk_bf16(v0, v1);
            pw.y = cvtpk_bf16(v2, v3);
            *(uint2*)(wb + ((i*32 + l4*8) ^ swz)) = pw;
          }
        }
        #pragma unroll
        for (int kk = 0; kk < 2; ++kk){
          short8 ap[2], bv[4];
          #pragma unroll
          for (int mf = 0; mf < 2; ++mf){
            int r = wid*32 + mf*16 + n15;
            int sl = (kk*4 + l4) ^ (r & 7);
            ap[mf] = *reinterpret_cast<const short8*>((const char*)Ps + r*128 + sl*16);
          }
          #pragma unroll
          for (int nf = 0; nf < 4; ++nf){
            int r = nf*16 + n15;
            int sl = (kk*4 + l4) ^ (r & 7);
            bv[nf] = *reinterpret_cast<const short8*>(vcur + r*128 + sl*16);
          }
          #pragma unroll
          for (int mf = 0; mf < 2; ++mf)
            #pragma unroll
            for (int nf = 0; nf < 4; ++nf)
              o[mf][nf] = __builtin_amdgcn_mfma_f32_16x16x32_bf16(ap[mf], bv[nf], o[mf][nf], 0,0,0);
        }
      }
      if (willstage) asm volatile("s_waitcnt vmcnt(4)" ::: "memory");
      else           asm volatile("s_waitcnt vmcnt(0)" ::: "memory");
      __syncthreads();
      curb = (curb == 2) ? 0 : curb + 1;
      sjb  = (sjb  == 2) ? 0 : sjb  + 1;
    }
    // epilogue: o -> Ps (wave-local, swizzled) -> coalesced global; + GN partials
    #pragma unroll
    for (int mf = 0; mf < 2; ++mf)
      #pragma unroll
      for (int nf = 0; nf < 4; ++nf)
        #pragma unroll
        for (int r = 0; r < 4; ++r){
          int trow = wid*32 + mf*16 + l4*4 + r;
          int d = nf*16 + n15;
          float v = o[mf][nf][r];
          gs += v; gq += v*v;
          *(unsigned short*)((char*)Ps + trow*128 + ((2*d) ^ ((trow & 7) << 4))) = f2bf(v);
        }
    asm volatile("s_waitcnt lgkmcnt(0)" ::: "memory");
    #pragma unroll
    for (int rr = 0; rr < 4; ++rr){
      int row = wid*32 + rr*8 + (lane >> 3);
      int off = (((lane & 7) << 4) ^ ((row & 7) << 4));
      uint4 v = *(const uint4*)((const char*)Ps + row*128 + off);
      *(uint4*)(rp + (long)(t0 + row)*64 + ((lane & 7) << 3)) = v;
    }
    __syncthreads();                              // protect Ps/Qs before next p staging
  }
  #pragma unroll
  for (int off = 32; off > 0; off >>= 1){
    gs += __shfl_down(gs, off);
    gq += __shfl_down(gq, off);
  }
  if (lane == 0){ gred[0][wid] = gs; gred[1][wid] = gq; }
  __syncthreads();
  if (tid == 0){
    gnp[(bh*4 + qpair)*2]   = gred[0][0]+gred[0][1]+gred[0][2]+gred[0][3];
    gnp[(bh*4 + qpair)*2+1] = gred[1][0]+gred[1][1]+gred[1][2]+gred[1][3];
  }
}

// ---------------- K^T V partials (LDS-transpose vector-FMA) ----------------
__global__ __launch_bounds__(256) void k_kvpart(const unsigned short* __restrict__ kb,
                                                const unsigned short* __restrict__ vtb,
                                                float* __restrict__ part){
  __shared__ unsigned short Kt[64*64];
  __shared__ unsigned int   Vt32[64*33];
  const int id = blockIdx.x;
  const int lin = (id & 7)*64 + (id >> 3);
  const int tc = lin & 3, bh = lin >> 2;
  const int tid = threadIdx.x;
  const int d0 = (tid >> 4) << 2;
  const int e0 = (tid & 15) << 2;
  const unsigned short* kp = kb + (long)bh*65536;
  const unsigned short* vp = vtb + (long)bh*65536;
  float acc[4][4] = {{0.f}};
  for (int tt = 0; tt < 4; ++tt){
    const int tb = tc*256 + tt*64;
    __syncthreads();
    {
      int rr0 = tid >> 3, off = (tid & 7) * 8;
      for (int c = 0; c < 2; ++c){
        int r = c*32 + rr0;
        *reinterpret_cast<uint4*>(&Kt[r*64 + off]) =
            *reinterpret_cast<const uint4*>(&kp[(long)(tb + r)*64 + off]);
        uint4 vv = *reinterpret_cast<const uint4*>(&vp[(long)r*1024 + tb + off]);
        unsigned int* dv = &Vt32[r*33 + (off >> 1)];
        dv[0] = vv.x; dv[1] = vv.y; dv[2] = vv.z; dv[3] = vv.w;
      }
    }
    __syncthreads();
    const unsigned short* Vt = (const unsigned short*)Vt32;
    for (int t = 0; t < 64; ++t){
      float kv[4], vv[4];
      #pragma unroll
      for (int i = 0; i < 4; ++i) kv[i] = bf2f(Kt[t*64 + d0 + i]);
      #pragma unroll
      for (int i = 0; i < 4; ++i) vv[i] = bf2f(Vt[(e0 + i)*66 + t]);
      #pragma unroll
      for (int i = 0; i < 4; ++i)
        #pragma unroll
        for (int j = 0; j < 4; ++j) acc[i][j] += kv[i]*vv[j];
    }
  }
  float* pp = part + ((long)(tc*128 + bh) << 12);
  for (int i = 0; i < 4; ++i)
    for (int j = 0; j < 4; ++j)
      pp[(d0+i)*64 + e0 + j] = acc[i][j];
}

// kvfin + GroupNorm stage-2 fused
__global__ __launch_bounds__(256) void k_kvfin(const float* __restrict__ part,
                                               const float* __restrict__ pk,
                                               float* __restrict__ okv,
                                               const float* __restrict__ gnp,
                                               float* __restrict__ musig){
  if (blockIdx.x == 0 && threadIdx.x < 8){
    int b = threadIdx.x;
    float S = 0.f, Q = 0.f;
    for (int g = 0; g < 64; ++g){ S += gnp[b*128 + g*2]; Q += gnp[b*128 + g*2 + 1]; }
    float mu  = S * (1.0f/1048576.0f);
    float var = Q * (1.0f/1048576.0f) - mu*mu;
    musig[b*2]   = mu;
    musig[b*2+1] = rsqrtf(var + 1e-5f);
  }
  int i = blockIdx.x*256 + threadIdx.x;
  int h = i >> 12;
  float acc = 0.f;
  for (int tc = 0; tc < 4; ++tc)
    for (int b = 0; b < 8; ++b)
      acc += part[((long)(tc*128 + b*16 + h) << 12) + (i & 4095)];
  float gamma = 1.0f - exp2f(-5.0f - (float)h);
  okv[i] = gamma * pk[i] + acc * 0.125f;
}

__global__ __launch_bounds__(256) void k_gnnorm(const unsigned short* __restrict__ rbuf,
                                                const float* __restrict__ musig,
                                                const float* __restrict__ gw,
                                                const float* __restrict__ gb,
                                                float* __restrict__ out){
  const int n8 = TKN*1024/8;
  for (int idx = blockIdx.x*256 + threadIdx.x; idx < n8; idx += gridDim.x*256){
    int o = idx*8;
    int c = o & 1023;
    int t = (o >> 10) & 1023;
    int b = o >> 20;
    int h = c >> 6, d = c & 63;
    short8 v = *reinterpret_cast<const short8*>(rbuf + ((long)(b*16 + h) << 16) + t*64 + d);
    float rs = musig[b*2+1];
    float a = gw[h]*rs, b2 = gb[h] - musig[b*2]*a;
    float4 o0, o1;
    o0.x = bf2f((unsigned short)v[0])*a + b2;
    o0.y = bf2f((unsigned short)v[1])*a + b2;
    o0.z = bf2f((unsigned short)v[2])*a + b2;
    o0.w = bf2f((unsigned short)v[3])*a + b2;
    o1.x = bf2f((unsigned short)v[4])*a + b2;
    o1.y = bf2f((unsigned short)v[5])*a + b2;
    o1.z = bf2f((unsigned short)v[6])*a + b2;
    o1.w = bf2f((unsigned short)v[7])*a + b2;
    *reinterpret_cast<float4*>(out + o)     = o0;
    *reinterpret_cast<float4*>(out + o + 4) = o1;
  }
}

extern "C" void kernel_launch(void* const* d_in, const int* in_sizes, int n_in,
                              void* d_out, int out_size, void* d_ws, size_t ws_size,
                              hipStream_t stream){
  const float* x  = (const float*)d_in[0];
  const float* pk = (const float*)d_in[1];
  const float* w  = (const float*)d_in[2];
  const float* gw = (const float*)d_in[3];
  const float* gb = (const float*)d_in[4];
  float* out = (float*)d_out;
  char* ws = (char*)d_ws;

  unsigned short* Xb  = (unsigned short*)(ws);                 // 16 MB (aliased by KVp later)
  unsigned short* WTb = (unsigned short*)(ws + 16777216);      //  6 MB
  unsigned short* Qb  = (unsigned short*)(ws + 23068672);      // 16 MB
  unsigned short* Kb  = (unsigned short*)(ws + 39845888);      // 16 MB
  unsigned short* VTb = (unsigned short*)(ws + 56623104);      // 16 MB
  unsigned short* PKt = (unsigned short*)(ws + 73400320);      // 128 KB
  unsigned short* Rb  = (unsigned short*)(ws + 73531392);      // 16 MB (bf16)
  float* KVp = (float*)(ws);                                   // aliases Xb (dead after gemm)
  float* GNp = (float*)(ws + 90308608);                        // 4 KB
  float* MuS = (float*)(ws + 90312704);                        // 64 B

  k_cvt    <<<dim3(3072),    dim3(256), 0, stream>>>(x, w, pk, Xb, WTb, PKt);
  k_gemm   <<<dim3(24, 64),  dim3(256), 0, stream>>>(Xb, WTb, Qb, Kb, VTb);
  k_kvpart <<<dim3(512),     dim3(256), 0, stream>>>(Kb, VTb, KVp);
  k_attn   <<<dim3(512),     dim3(256), 0, stream>>>(Qb, Kb, VTb, PKt, Rb, GNp);
  k_kvfin  <<<dim3(256),     dim3(256), 0, stream>>>(KVp, pk, out + 8388608, GNp, MuS);
  k_gnnorm <<<dim3(1024),    dim3(256), 0, stream>>>(Rb, MuS, gw, gb, out);
}